// Round 16
// baseline (1883.726 us; speedup 1.0000x reference)
//
#include <hip/hip_runtime.h>
#include <hip/hip_fp16.h>
#include <math.h>

constexpr int BB  = 4;
constexpr int NN  = 4096;
constexpr int KK  = 20;
constexpr int NKK = NN * KK;     // 81920 positions per batch
constexpr int TPOS = BB * NKK;   // 327680 total positions
constexpr int NMASK = NN - 1;

#define DEVFN __device__ __forceinline__

DEVFN float lrelu_f(float v) { return v >= 0.f ? v : 0.2f * v; }
DEVFN unsigned fenc(float f) { unsigned u = __float_as_uint(f); return (u & 0x80000000u) ? ~u : (u | 0x80000000u); }

// ---------------- kNN via radix-select, 2 queries per block (128-thread halves) ----------------
// Keys/thresholds/tie-ranks computed with bit-exact reference formulas -> indices identical to R15.
template<int CSTRIDE>
__global__ __launch_bounds__(256) void knn_kernel(const float* __restrict__ xin, int* __restrict__ idxout)
{
    __shared__ float sx[NN], sy[NN], sz[NN];             // 48 KB
    __shared__ unsigned shist[2][256];                   // 2 KB
    __shared__ unsigned long long spool64[2][128];       // 2 KB (scollv overlay: 256 u32 per half)
    __shared__ unsigned sres[2][2];
    __shared__ unsigned scnt[2][2];
    const int tid  = threadIdx.x;
    const int half = tid >> 7;                           // which query of the pair
    const int t2   = tid & 127;                          // id within half
    const int b  = blockIdx.x >> 8;                      // 256 blocks per batch
    const int q0 = (blockIdx.x & 255) * 16;              // 16 queries per block
    for (int i = tid; i < NN; i += 256) {
        const float4 rc = *reinterpret_cast<const float4*>(xin + (size_t)(b*NN + i) * CSTRIDE);
        sx[i] = rc.x; sy[i] = rc.y; sz[i] = rc.z;
    }

    unsigned* scollv = reinterpret_cast<unsigned*>(&spool64[half][0]);      // 256 u32, dead before scoll64 use
    unsigned long long* scoll64 = &spool64[half][0];                        // 128 u64

    for (int qq = 0; qq < 8; ++qq) {
        __syncthreads();                                 // staging done / prev pair fully consumed
        shist[half][t2] = 0; shist[half][t2 + 128] = 0;
        if (t2 == 0) { scnt[half][0] = 0; scnt[half][1] = 0; }
        const int qi = q0 + qq*2 + half;
        const float qx = sx[qi], qy = sy[qi], qz = sz[qi];
        const float nxx = -__fadd_rn(__fadd_rn(__fmul_rn(qx,qx), __fmul_rn(qy,qy)), __fmul_rn(qz,qz));
        __syncthreads();
        unsigned ukey[NN/128];                           // 32 keys in VGPRs
#pragma unroll
        for (int i = 0; i < NN/128; ++i) {
            const int m = t2 + (i << 7);
            float cx = sx[m], cy = sy[m], cz = sz[m];
            float cw  = __fadd_rn(__fadd_rn(__fmul_rn(cx,cx), __fmul_rn(cy,cy)), __fmul_rn(cz,cz));
            float dot = __fadd_rn(__fadd_rn(__fmul_rn(qx,cx), __fmul_rn(qy,cy)), __fmul_rn(qz,cz));
            float pd  = __fsub_rn(__fsub_rn(nxx, __fmul_rn(-2.f, dot)), cw);
            unsigned u = fenc(pd);
            ukey[i] = u;
            atomicAdd(&shist[half][u >> 24], 1u);
        }
        __syncthreads();
        if (t2 < 64) {                                   // waves 0 (half 0) and 2 (half 1)
            const int base = 255 - t2*4;
            unsigned h0 = shist[half][base], h1 = shist[half][base-1], h2 = shist[half][base-2], h3 = shist[half][base-3];
            unsigned s = h0 + h1 + h2 + h3;
            unsigned c = s;
#pragma unroll
            for (int off = 1; off < 64; off <<= 1) { unsigned t = __shfl_up(c, off, 64); if (t2 >= off) c += t; }
            unsigned cprev = c - s;
            if (c >= KK && cprev < KK) {
                unsigned cc = cprev; int bb = base;
                if (cc + h0 < KK) { cc += h0; bb = base-1;
                    if (cc + h1 < KK) { cc += h1; bb = base-2;
                        if (cc + h2 < KK) { cc += h2; bb = base-3; } } }
                sres[half][0] = (unsigned)bb; sres[half][1] = KK - cc;
            }
        }
        __syncthreads();
        const unsigned b0 = sres[half][0], K1 = sres[half][1];
        shist[half][t2] = 0; shist[half][t2 + 128] = 0;
        __syncthreads();
#pragma unroll
        for (int i = 0; i < NN/128; ++i) {
            unsigned u = ukey[i];
            if ((u >> 24) == b0) atomicAdd(&shist[half][(u >> 16) & 255u], 1u);
        }
        __syncthreads();
        if (t2 < 64) {
            const int base = 255 - t2*4;
            unsigned h0 = shist[half][base], h1 = shist[half][base-1], h2 = shist[half][base-2], h3 = shist[half][base-3];
            unsigned s = h0 + h1 + h2 + h3;
            unsigned c = s;
#pragma unroll
            for (int off = 1; off < 64; off <<= 1) { unsigned t = __shfl_up(c, off, 64); if (t2 >= off) c += t; }
            unsigned cprev = c - s;
            if (c >= K1 && cprev < K1) {
                unsigned cc = cprev; int bb = base;
                if (cc + h0 < K1) { cc += h0; bb = base-1;
                    if (cc + h1 < K1) { cc += h1; bb = base-2;
                        if (cc + h2 < K1) { cc += h2; bb = base-3; } } }
                sres[half][0] = (unsigned)bb; sres[half][1] = K1 - cc;
            }
        }
        __syncthreads();
        const unsigned prefix16 = (b0 << 8) | sres[half][0];
        const unsigned K2 = sres[half][1];
#pragma unroll
        for (int i = 0; i < NN/128; ++i) {
            unsigned u = ukey[i];
            if ((u >> 16) == prefix16) {
                unsigned pos = atomicAdd(&scnt[half][0], 1u);
                if (pos < 256u) scollv[pos] = u;
            }
        }
        __syncthreads();
        {
            int cb = (int)scnt[half][0]; if (cb > 256) cb = 256;
            for (int cand = t2; cand < cb; cand += 128) {       // cover up to 256 with 128 threads
                unsigned v = scollv[cand];
                unsigned ng = 0, ne = 0;
                for (int j = 0; j < cb; ++j) {
                    unsigned w = scollv[j];
                    ng += (w > v); ne += (w == v);
                }
                if (ng < K2 && ng + ne >= K2) sres[half][0] = v; // unique value
            }
        }
        __syncthreads();
        const unsigned W = sres[half][0];
#pragma unroll
        for (int i = 0; i < NN/128; ++i) {
            const int m = t2 + (i << 7);
            unsigned u = ukey[i];
            if (u >= W) {
                unsigned pos = atomicAdd(&scnt[half][1], 1u);
                if (pos < 128u) scoll64[pos] = ((unsigned long long)u << 32) | (unsigned)(NN-1 - m);
            }
        }
        __syncthreads();
        {
            int c2 = (int)scnt[half][1]; if (c2 > 128) c2 = 128;
            if (t2 < c2) {
                unsigned long long kv = scoll64[t2];
                int rank = 0;
                for (int j = 0; j < c2; ++j) rank += (scoll64[j] > kv);
                if (rank < KK) {
                    int* op = idxout + ((size_t)(b*NN + qi)) * KK;
                    op[rank] = (NN-1) - (int)(kv & 0xFFFFFFFFull);
                }
            }
        }
    }
}

// ---------------- u/v precompute: u_p = W_a x_p, v_p = (W_b - W_a) x_p ----------------
template<int CINH, int CSTRIDE>
__global__ __launch_bounds__(64) void uv_kernel(const float* __restrict__ xin, const float* __restrict__ w,
                                                float* __restrict__ ub, float* __restrict__ vb)
{
    __shared__ float sp[32][CINH];
    const int lane = threadIdx.x;
    float wa[CINH], wd[CINH];
#pragma unroll
    for (int c = 0; c < CINH; ++c) {
        float a = w[lane*(2*CINH) + c];
        wa[c] = a;
        wd[c] = w[lane*(2*CINH) + CINH + c] - a;
    }
    const int p0 = blockIdx.x * 32;
    for (int i = lane; i < 32*CINH; i += 64) {
        int pi = i / CINH, c = i % CINH;
        sp[pi][c] = xin[(size_t)(p0 + pi)*CSTRIDE + c];
    }
    __syncthreads();
    for (int pi = 0; pi < 32; ++pi) {
        float au = 0.f, av = 0.f;
#pragma unroll
        for (int c = 0; c < CINH; ++c) {
            float xv = sp[pi][c];
            au = fmaf(wa[c], xv, au);
            av = fmaf(wd[c], xv, av);
        }
        ub[(size_t)(p0 + pi)*64 + lane] = au;
        vb[(size_t)(p0 + pi)*64 + lane] = av;
    }
}

// ---------------- gather-add stats, 1 row per wave (grid 4096 x 256): o = u[j] + v[n] ----------------
// Per-row float exprs identical to R15; only f64 partial-sum grouping changes (safe class, cf. R9).
template<bool STOREMAX>
__global__ __launch_bounds__(256) void gstat_kernel(const float* __restrict__ ub, const float* __restrict__ vb,
    const int* __restrict__ idx, float* __restrict__ xraw,
    double* __restrict__ ssum, double* __restrict__ ssq)
{
    const int lane = threadIdx.x & 63;
    const int wv   = threadIdx.x >> 6;
    const int g = blockIdx.x * 4 + wv;          // one row per wave
    const int b = g >> 12;                      // g / NN
    const float v = vb[(size_t)g*64 + lane];
    double lsum = 0.0, lsq = 0.0;
    float vmax = -INFINITY;
    for (int k = 0; k < KK; ++k) {
        const int j = idx[(size_t)g*KK + k] & NMASK;
        float o = ub[(size_t)(b*NN + j)*64 + lane] + v;
        if constexpr (STOREMAX) vmax = fmaxf(vmax, o);
        lsum += (double)o; lsq += (double)o*(double)o;
    }
    if constexpr (STOREMAX) xraw[(size_t)g*64 + lane] = vmax;
    atomicAdd(&ssum[b*64+lane], lsum);
    atomicAdd(&ssq [b*64+lane], lsq);
}

// ---------------- stage 1 pass B (exact, frozen): conv1 -> norm/lrelu -> conv2 ----------------
__global__ __launch_bounds__(64) void s1b_kernel(const float* __restrict__ x, const int* __restrict__ idx,
    const float* __restrict__ w1, const float* __restrict__ w2,
    const float* __restrict__ m1, const float* __restrict__ r1,
    float* __restrict__ xraw, double* __restrict__ ssum, double* __restrict__ ssq)
{
    __shared__ float sh[64];
    const int lane = threadIdx.x;
    float wr1[8];
#pragma unroll
    for (int c = 0; c < 8; ++c) wr1[c] = w1[lane*8 + c];
    float wr2[64];
#pragma unroll
    for (int c = 0; c < 64; ++c) wr2[c] = w2[lane*64 + c];
    const int g0 = blockIdx.x * 8;
    const int b = g0 / NN;
    const float mm = m1[b*64+lane], rr = r1[b*64+lane];
    double lsum = 0.0, lsq = 0.0;
    for (int ni = 0; ni < 8; ++ni) {
        const int g = g0 + ni;
        const float4 ct = *reinterpret_cast<const float4*>(x + (size_t)g*4);
        float vmax = -INFINITY;
        for (int k = 0; k < KK; ++k) {
            const int j = idx[(size_t)g*KK + k] & NMASK;
            const float4 nb = *reinterpret_cast<const float4*>(x + (size_t)(b*NN + j)*4);
            float o1 = wr1[0]*(nb.x-ct.x) + wr1[1]*(nb.y-ct.y) + wr1[2]*(nb.z-ct.z) + wr1[3]*(nb.w-ct.w)
                     + wr1[4]*ct.x + wr1[5]*ct.y + wr1[6]*ct.z + wr1[7]*ct.w;
            float h = lrelu_f((o1 - mm) * rr);
            __syncthreads();
            sh[lane] = h;
            __syncthreads();
            float acc = 0.f;
#pragma unroll
            for (int c = 0; c < 64; c += 4) {
                const float4 hv = *reinterpret_cast<const float4*>(&sh[c]);
                acc += wr2[c]*hv.x + wr2[c+1]*hv.y + wr2[c+2]*hv.z + wr2[c+3]*hv.w;
            }
            vmax = fmaxf(vmax, acc);
            lsum += (double)acc; lsq += (double)acc*(double)acc;
        }
        xraw[(size_t)g*64 + lane] = vmax;
    }
    atomicAdd(&ssum[b*64+lane], lsum);
    atomicAdd(&ssq [b*64+lane], lsq);
}

// ---------------- stage 2 pass B (exact, frozen): conv3 -> norm/lrelu -> conv4 ----------------
__global__ __launch_bounds__(64) void s2b_kernel(const float* __restrict__ xin, const int* __restrict__ idx,
    const float* __restrict__ w3, const float* __restrict__ w4,
    const float* __restrict__ m3, const float* __restrict__ r3,
    float* __restrict__ xraw, double* __restrict__ ssum, double* __restrict__ ssq)
{
    __shared__ float sf[128];
    __shared__ float sh[64];
    const int lane = threadIdx.x;
    float wr3[128];
#pragma unroll
    for (int c = 0; c < 128; ++c) wr3[c] = w3[lane*128 + c];
    float wr4[64];
#pragma unroll
    for (int c = 0; c < 64; ++c) wr4[c] = w4[lane*64 + c];
    const int g0 = blockIdx.x * 8;
    const int b = g0 / NN;
    const float mm = m3[b*64+lane], rr = r3[b*64+lane];
    double lsum = 0.0, lsq = 0.0;
    for (int ni = 0; ni < 8; ++ni) {
        const int g = g0 + ni;
        const float ctl = xin[(size_t)g*64 + lane];
        float vmax = -INFINITY;
        for (int k = 0; k < KK; ++k) {
            const int j = idx[(size_t)g*KK + k] & NMASK;
            const float nbl = xin[(size_t)(b*NN + j)*64 + lane];
            __syncthreads();
            sf[lane] = nbl - ctl;
            sf[64+lane] = ctl;
            __syncthreads();
            float o3 = 0.f;
#pragma unroll
            for (int c = 0; c < 128; c += 4) {
                const float4 fv = *reinterpret_cast<const float4*>(&sf[c]);
                o3 += wr3[c]*fv.x + wr3[c+1]*fv.y + wr3[c+2]*fv.z + wr3[c+3]*fv.w;
            }
            float h = lrelu_f((o3 - mm) * rr);
            __syncthreads();
            sh[lane] = h;
            __syncthreads();
            float acc = 0.f;
#pragma unroll
            for (int c = 0; c < 64; c += 4) {
                const float4 hv = *reinterpret_cast<const float4*>(&sh[c]);
                acc += wr4[c]*hv.x + wr4[c+1]*hv.y + wr4[c+2]*hv.z + wr4[c+3]*hv.w;
            }
            vmax = fmaxf(vmax, acc);
            lsum += (double)acc; lsq += (double)acc*(double)acc;
        }
        xraw[(size_t)g*64 + lane] = vmax;
    }
    atomicAdd(&ssum[b*64+lane], lsum);
    atomicAdd(&ssq [b*64+lane], lsq);
}

// ---------------- stats finalize ----------------
__global__ void fin_kernel(const double* __restrict__ ssum, const double* __restrict__ ssq,
                           float* __restrict__ meanp, float* __restrict__ rstdp, int total, double invn)
{
    int t = blockIdx.x*256 + threadIdx.x;
    if (t >= total) return;
    double m = ssum[t]*invn;
    double v = ssq[t]*invn - m*m;
    meanp[t] = (float)m;
    rstdp[t] = (float)(1.0 / sqrt(v + 1e-5));
}

// float4 finx: bit-identical per element (elementwise op)
__global__ void finx_kernel(float* __restrict__ xv, const float* __restrict__ m, const float* __restrict__ r)
{
    int t = blockIdx.x*256 + threadIdx.x;   // over B*NN*16 float4s
    int c0 = (t & 15) * 4;
    int b = t >> 16;                        // NN*16 float4s per batch
    float4 v = *reinterpret_cast<float4*>(xv + (size_t)t*4);
    v.x = lrelu_f((v.x - m[b*64+c0+0]) * r[b*64+c0+0]);
    v.y = lrelu_f((v.y - m[b*64+c0+1]) * r[b*64+c0+1]);
    v.z = lrelu_f((v.z - m[b*64+c0+2]) * r[b*64+c0+2]);
    v.w = lrelu_f((v.w - m[b*64+c0+3]) * r[b*64+c0+3]);
    *reinterpret_cast<float4*>(xv + (size_t)t*4) = v;
}

__global__ void transw_kernel(const float* __restrict__ w, float* __restrict__ wT, int O, int C, int rs, int off)
{
    int t = blockIdx.x*256 + threadIdx.x;
    if (t >= O*C) return;
    int o = t % O, c = t / O;
    wT[t] = w[(size_t)o*rs + off + c];
}

// conv7 pass A: 192(cat) -> 512 (g-broadcast term cancels exactly under in1d), stats + out7 fp16
__global__ __launch_bounds__(256) void conv7a_kernel(
    const float* __restrict__ x1, const float* __restrict__ x2, const float* __restrict__ x3,
    const float* __restrict__ wT,
    __half* __restrict__ out7h, double* __restrict__ ssum, double* __restrict__ ssq)
{
    __shared__ float si[32][192];
    const int b = blockIdx.z, nbase = blockIdx.x*32;
    const int o = blockIdx.y*256 + threadIdx.x;
    for (int i = threadIdx.x; i < 32*192; i += 256) {
        int nl = i/192, c = i%192;
        size_t base = (size_t)(b*NN + nbase + nl)*64;
        si[nl][c] = (c < 64) ? x1[base + c] : (c < 128) ? x2[base + c - 64] : x3[base + c - 128];
    }
    __syncthreads();
    float acc[32];
#pragma unroll
    for (int n = 0; n < 32; ++n) acc[n] = 0.f;
    for (int c = 0; c < 192; ++c) {
        float wv = wT[(size_t)c*512 + o];
#pragma unroll
        for (int n = 0; n < 32; ++n) acc[n] = fmaf(wv, si[n][c], acc[n]);
    }
    double ps = 0.0, pq = 0.0;
#pragma unroll
    for (int n = 0; n < 32; ++n) {
        out7h[(size_t)(b*NN + nbase + n)*512 + o] = __float2half(acc[n]);
        ps += (double)acc[n]; pq += (double)acc[n]*(double)acc[n];
    }
    atomicAdd(&ssum[b*512+o], ps);
    atomicAdd(&ssq [b*512+o], pq);
}

// conv8 only: read out7h, norm+lrelu -> LDS, conv8 -> out8 + stats8
__global__ __launch_bounds__(256) void conv8k_kernel(
    const __half* __restrict__ out7h, const float* __restrict__ m7, const float* __restrict__ r7,
    const float* __restrict__ wT8,
    float* __restrict__ out8, double* __restrict__ ssum, double* __restrict__ ssq)
{
    __shared__ float h7[16][512];    // 32 KB
    const int b = blockIdx.y, nbase = blockIdx.x*16;
    const int tid = threadIdx.x;
    for (int i = tid; i < 16*512; i += 256) {
        int nl = i >> 9, c = i & 511;
        float v = __half2float(out7h[(size_t)(b*NN + nbase + nl)*512 + c]);
        h7[nl][c] = lrelu_f((v - m7[b*512+c]) * r7[b*512+c]);
    }
    __syncthreads();
    const int o = tid;
    float acc8[16];
#pragma unroll
    for (int n = 0; n < 16; ++n) acc8[n] = 0.f;
    for (int c = 0; c < 512; ++c) {
        float wv = wT8[(size_t)c*256 + o];
#pragma unroll
        for (int n = 0; n < 16; ++n) acc8[n] = fmaf(wv, h7[n][c], acc8[n]);
    }
    double ps = 0.0, pq = 0.0;
#pragma unroll
    for (int n = 0; n < 16; ++n) {
        out8[(size_t)(b*NN + nbase + n)*256 + o] = acc8[n];
        ps += (double)acc8[n]; pq += (double)acc8[n]*(double)acc8[n];
    }
    atomicAdd(&ssum[b*256+o], ps);
    atomicAdd(&ssq [b*256+o], pq);
}

// conv9: 256 -> 2
__global__ __launch_bounds__(256) void conv9_kernel(const float* __restrict__ in8,
    const float* __restrict__ meanp, const float* __restrict__ rstdp,
    const float* __restrict__ w9, float* __restrict__ outp)
{
    const int lane = threadIdx.x & 63, wv = threadIdx.x >> 6;
    const int ng = blockIdx.x*4 + wv;
    const int b = ng / NN;
    const int c0 = lane*4;
    const float4 v4 = *reinterpret_cast<const float4*>(&in8[(size_t)ng*256 + c0]);
    float vv[4] = {v4.x, v4.y, v4.z, v4.w};
    float a0 = 0.f, a1 = 0.f;
#pragma unroll
    for (int i = 0; i < 4; ++i) {
        int c = c0 + i;
        float a = lrelu_f((vv[i] - meanp[b*256+c]) * rstdp[b*256+c]);
        a0 = fmaf(w9[c],     a, a0);
        a1 = fmaf(w9[256+c], a, a1);
    }
#pragma unroll
    for (int off = 32; off > 0; off >>= 1) {
        a0 += __shfl_down(a0, off, 64);
        a1 += __shfl_down(a1, off, 64);
    }
    if (lane == 0) { outp[(size_t)ng*2 + 0] = a0; outp[(size_t)ng*2 + 1] = a1; }
}

extern "C" void kernel_launch(void* const* d_in, const int* in_sizes, int n_in,
                              void* d_out, int out_size, void* d_ws, size_t ws_size,
                              hipStream_t stream)
{
    const float* x  = (const float*)d_in[0];
    const float* w1 = (const float*)d_in[1];
    const float* w2 = (const float*)d_in[2];
    const float* w3 = (const float*)d_in[3];
    const float* w4 = (const float*)d_in[4];
    const float* w5 = (const float*)d_in[5];
    const float* w7 = (const float*)d_in[7];
    const float* w8 = (const float*)d_in[8];
    const float* w9 = (const float*)d_in[9];
    float* outp = (float*)d_out;

    char* ws = (char*)d_ws;
    size_t off = 0;
    auto alloc = [&](size_t bytes) -> void* {
        void* p = ws + off;
        off = (off + bytes + 255) & ~(size_t)255;
        return p;
    };
    double* dstats = (double*)alloc((size_t)16896 * 8);
    unsigned* u6max = (unsigned*)alloc((size_t)4096 * 4);   // layout stability (unused)
    float* fstats = (float*)alloc((size_t)14848 * 4);
    int*   idxb  = (int*)  alloc((size_t)TPOS * 4);
    float* wT7   = (float*)alloc((size_t)512*192*4);
    float* wT8   = (float*)alloc((size_t)256*512*4);
    // union region: ubuf+vbuf (stages) / out7h (head)
    char*  sc17  = (char*) alloc((size_t)BB*NN*512*2);
    float* ubuf  = (float*)sc17;
    float* vbuf  = (float*)(sc17 + (size_t)BB*NN*64*4);
    __half* out7h = (__half*)sc17;
    float* x1v   = (float*)alloc((size_t)BB*NN*64*4);
    float* x2v   = (float*)alloc((size_t)BB*NN*64*4);
    float* x3v   = (float*)alloc((size_t)BB*NN*64*4);
    float* out8  = (float*)alloc((size_t)BB*NN*256*4);

    (void)u6max;
    double* d1 = dstats;           double* d2 = dstats + 512;
    double* d3 = dstats + 1024;    double* d4 = dstats + 1536;
    double* d5 = dstats + 2048;
    double* d7sum = dstats + 10752; double* d7sq = d7sum + 2048;
    double* d8sum = dstats + 14848; double* d8sq = d8sum + 1024;
    float* m1 = fstats;        float* r1 = fstats + 256;
    float* m2 = fstats + 512;  float* r2 = fstats + 768;
    float* m3 = fstats + 1024; float* r3 = fstats + 1280;
    float* m4 = fstats + 1536; float* r4 = fstats + 1792;
    float* m5 = fstats + 2048; float* r5 = fstats + 2304;
    float* m7 = fstats + 6656; float* r7 = fstats + 8704;
    float* m8 = fstats + 12800; float* r8 = fstats + 13824;

    hipMemsetAsync(dstats, 0, (size_t)16896*8 + (size_t)4096*4, stream);

    transw_kernel<<<384, 256, 0, stream>>>(w7, wT7, 512, 192, 1216, 1024);
    transw_kernel<<<512, 256, 0, stream>>>(w8, wT8, 256, 512, 512, 0);

    // ---- stage 1 ----
    knn_kernel<4><<<1024, 256, 0, stream>>>(x, idxb);
    uv_kernel<4, 4><<<512, 64, 0, stream>>>(x, w1, ubuf, vbuf);
    gstat_kernel<false><<<4096, 256, 0, stream>>>(ubuf, vbuf, idxb, nullptr, d1, d1+256);
    fin_kernel<<<1, 256, 0, stream>>>(d1, d1+256, m1, r1, 256, 1.0/81920.0);
    s1b_kernel<<<2048, 64, 0, stream>>>(x, idxb, w1, w2, m1, r1, x1v, d2, d2+256);
    fin_kernel<<<1, 256, 0, stream>>>(d2, d2+256, m2, r2, 256, 1.0/81920.0);
    finx_kernel<<<1024, 256, 0, stream>>>(x1v, m2, r2);

    // ---- stage 2 ----
    knn_kernel<64><<<1024, 256, 0, stream>>>(x1v, idxb);
    uv_kernel<64, 64><<<512, 64, 0, stream>>>(x1v, w3, ubuf, vbuf);
    gstat_kernel<false><<<4096, 256, 0, stream>>>(ubuf, vbuf, idxb, nullptr, d3, d3+256);
    fin_kernel<<<1, 256, 0, stream>>>(d3, d3+256, m3, r3, 256, 1.0/81920.0);
    s2b_kernel<<<2048, 64, 0, stream>>>(x1v, idxb, w3, w4, m3, r3, x2v, d4, d4+256);
    fin_kernel<<<1, 256, 0, stream>>>(d4, d4+256, m4, r4, 256, 1.0/81920.0);
    finx_kernel<<<1024, 256, 0, stream>>>(x2v, m4, r4);

    // ---- stage 3: fully u/v (x3v feeds no kNN) ----
    knn_kernel<64><<<1024, 256, 0, stream>>>(x2v, idxb);
    uv_kernel<64, 64><<<512, 64, 0, stream>>>(x2v, w5, ubuf, vbuf);
    gstat_kernel<true><<<4096, 256, 0, stream>>>(ubuf, vbuf, idxb, x3v, d5, d5+256);
    fin_kernel<<<1, 256, 0, stream>>>(d5, d5+256, m5, r5, 256, 1.0/81920.0);
    finx_kernel<<<1024, 256, 0, stream>>>(x3v, m5, r5);

    // ---- head (conv6/g path dropped: cancels exactly under in1d) ----
    conv7a_kernel<<<dim3(128, 2, 4), 256, 0, stream>>>(x1v, x2v, x3v, wT7, out7h, d7sum, d7sq);
    fin_kernel<<<8, 256, 0, stream>>>(d7sum, d7sq, m7, r7, 2048, 1.0/4096.0);
    conv8k_kernel<<<dim3(256, 4), 256, 0, stream>>>(out7h, m7, r7, wT8, out8, d8sum, d8sq);
    fin_kernel<<<4, 256, 0, stream>>>(d8sum, d8sq, m8, r8, 1024, 1.0/4096.0);
    conv9_kernel<<<4096, 256, 0, stream>>>(out8, m8, r8, w9, outp);
}

// Round 17
// 1558.127 us; speedup vs baseline: 1.2090x; 1.2090x over previous
//
#include <hip/hip_runtime.h>
#include <hip/hip_fp16.h>
#include <math.h>

constexpr int BB  = 4;
constexpr int NN  = 4096;
constexpr int KK  = 20;
constexpr int NKK = NN * KK;     // 81920 positions per batch
constexpr int TPOS = BB * NKK;   // 327680 total positions
constexpr int NMASK = NN - 1;

#define DEVFN __device__ __forceinline__

DEVFN float lrelu_f(float v) { return v >= 0.f ? v : 0.2f * v; }
DEVFN unsigned fenc(float f) { unsigned u = __float_as_uint(f); return (u & 0x80000000u) ? ~u : (u | 0x80000000u); }

// ---------------- kNN via radix-select, keys in registers: top-20 by pd, bit-exact formula ----------------
template<int CSTRIDE>
__global__ __launch_bounds__(256) void knn_kernel(const float* __restrict__ xin, int* __restrict__ idxout)
{
    __shared__ float sx[NN], sy[NN], sz[NN];         // 48 KB
    __shared__ unsigned shist[256];
    __shared__ unsigned scollv[256];
    __shared__ unsigned long long scoll64[128];
    __shared__ unsigned sres[2];
    __shared__ unsigned scnt[2];
    const int tid = threadIdx.x;
    const int b  = blockIdx.x >> 8;                  // 256 blocks per batch
    const int q0 = (blockIdx.x & 255) * 16;          // 16 queries per block
    for (int i = tid; i < NN; i += 256) {
        const float4 rc = *reinterpret_cast<const float4*>(xin + (size_t)(b*NN + i) * CSTRIDE);
        sx[i] = rc.x; sy[i] = rc.y; sz[i] = rc.z;
    }

    for (int qq = 0; qq < 16; ++qq) {
        __syncthreads();
        shist[tid] = 0;
        if (tid == 0) { scnt[0] = 0; scnt[1] = 0; }
        const int qi = q0 + qq;
        const float qx = sx[qi], qy = sy[qi], qz = sz[qi];
        const float nxx = -__fadd_rn(__fadd_rn(__fmul_rn(qx,qx), __fmul_rn(qy,qy)), __fmul_rn(qz,qz));
        __syncthreads();
        unsigned ukey[NN/256];                        // 16 keys in VGPRs
#pragma unroll
        for (int i = 0; i < NN/256; ++i) {
            const int m = tid + (i << 8);
            float cx = sx[m], cy = sy[m], cz = sz[m];
            float cw  = __fadd_rn(__fadd_rn(__fmul_rn(cx,cx), __fmul_rn(cy,cy)), __fmul_rn(cz,cz));
            float dot = __fadd_rn(__fadd_rn(__fmul_rn(qx,cx), __fmul_rn(qy,cy)), __fmul_rn(qz,cz));
            float pd  = __fsub_rn(__fsub_rn(nxx, __fmul_rn(-2.f, dot)), cw);
            unsigned u = fenc(pd);
            ukey[i] = u;
            atomicAdd(&shist[u >> 24], 1u);
        }
        __syncthreads();
        if (tid < 64) {
            const int base = 255 - tid*4;
            unsigned h0 = shist[base], h1 = shist[base-1], h2 = shist[base-2], h3 = shist[base-3];
            unsigned s = h0 + h1 + h2 + h3;
            unsigned c = s;
#pragma unroll
            for (int off = 1; off < 64; off <<= 1) { unsigned t = __shfl_up(c, off, 64); if (tid >= off) c += t; }
            unsigned cprev = c - s;
            if (c >= KK && cprev < KK) {
                unsigned cc = cprev; int bb = base;
                if (cc + h0 < KK) { cc += h0; bb = base-1;
                    if (cc + h1 < KK) { cc += h1; bb = base-2;
                        if (cc + h2 < KK) { cc += h2; bb = base-3; } } }
                sres[0] = (unsigned)bb; sres[1] = KK - cc;
            }
        }
        __syncthreads();
        const unsigned b0 = sres[0], K1 = sres[1];
        shist[tid] = 0;
        __syncthreads();
#pragma unroll
        for (int i = 0; i < NN/256; ++i) {
            unsigned u = ukey[i];
            if ((u >> 24) == b0) atomicAdd(&shist[(u >> 16) & 255u], 1u);
        }
        __syncthreads();
        if (tid < 64) {
            const int base = 255 - tid*4;
            unsigned h0 = shist[base], h1 = shist[base-1], h2 = shist[base-2], h3 = shist[base-3];
            unsigned s = h0 + h1 + h2 + h3;
            unsigned c = s;
#pragma unroll
            for (int off = 1; off < 64; off <<= 1) { unsigned t = __shfl_up(c, off, 64); if (tid >= off) c += t; }
            unsigned cprev = c - s;
            if (c >= K1 && cprev < K1) {
                unsigned cc = cprev; int bb = base;
                if (cc + h0 < K1) { cc += h0; bb = base-1;
                    if (cc + h1 < K1) { cc += h1; bb = base-2;
                        if (cc + h2 < K1) { cc += h2; bb = base-3; } } }
                sres[0] = (unsigned)bb; sres[1] = K1 - cc;
            }
        }
        __syncthreads();
        const unsigned prefix16 = (b0 << 8) | sres[0];
        const unsigned K2 = sres[1];
#pragma unroll
        for (int i = 0; i < NN/256; ++i) {
            unsigned u = ukey[i];
            if ((u >> 16) == prefix16) {
                unsigned pos = atomicAdd(&scnt[0], 1u);
                if (pos < 256u) scollv[pos] = u;
            }
        }
        __syncthreads();
        {
            int cb = (int)scnt[0]; if (cb > 256) cb = 256;
            if (tid < cb) {
                unsigned v = scollv[tid];
                unsigned ng = 0, ne = 0;
                for (int j = 0; j < cb; ++j) {
                    unsigned w = scollv[j];
                    ng += (w > v); ne += (w == v);
                }
                if (ng < K2 && ng + ne >= K2) sres[0] = v;
            }
        }
        __syncthreads();
        const unsigned W = sres[0];
#pragma unroll
        for (int i = 0; i < NN/256; ++i) {
            const int m = tid + (i << 8);
            unsigned u = ukey[i];
            if (u >= W) {
                unsigned pos = atomicAdd(&scnt[1], 1u);
                if (pos < 128u) scoll64[pos] = ((unsigned long long)u << 32) | (unsigned)(NN-1 - m);
            }
        }
        __syncthreads();
        {
            int c2 = (int)scnt[1]; if (c2 > 128) c2 = 128;
            if (tid < c2) {
                unsigned long long kv = scoll64[tid];
                int rank = 0;
                for (int j = 0; j < c2; ++j) rank += (scoll64[j] > kv);
                if (rank < KK) {
                    int* op = idxout + ((size_t)(b*NN + qi)) * KK;
                    op[rank] = (NN-1) - (int)(kv & 0xFFFFFFFFull);
                }
            }
        }
    }
}

// ---------------- u/v precompute: u_p = W_a x_p, v_p = (W_b - W_a) x_p ----------------
template<int CINH, int CSTRIDE>
__global__ __launch_bounds__(64) void uv_kernel(const float* __restrict__ xin, const float* __restrict__ w,
                                                float* __restrict__ ub, float* __restrict__ vb)
{
    __shared__ float sp[32][CINH];
    const int lane = threadIdx.x;
    float wa[CINH], wd[CINH];
#pragma unroll
    for (int c = 0; c < CINH; ++c) {
        float a = w[lane*(2*CINH) + c];
        wa[c] = a;
        wd[c] = w[lane*(2*CINH) + CINH + c] - a;
    }
    const int p0 = blockIdx.x * 32;
    for (int i = lane; i < 32*CINH; i += 64) {
        int pi = i / CINH, c = i % CINH;
        sp[pi][c] = xin[(size_t)(p0 + pi)*CSTRIDE + c];
    }
    __syncthreads();
    for (int pi = 0; pi < 32; ++pi) {
        float au = 0.f, av = 0.f;
#pragma unroll
        for (int c = 0; c < CINH; ++c) {
            float xv = sp[pi][c];
            au = fmaf(wa[c], xv, au);
            av = fmaf(wd[c], xv, av);
        }
        ub[(size_t)(p0 + pi)*64 + lane] = au;
        vb[(size_t)(p0 + pi)*64 + lane] = av;
    }
}

// ---------------- gather-add stats: o = u[j] + v[n]; f64 sum/sumsq; optional max->xraw ----------------
template<bool STOREMAX>
__global__ __launch_bounds__(64) void gstat_kernel(const float* __restrict__ ub, const float* __restrict__ vb,
    const int* __restrict__ idx, float* __restrict__ xraw,
    double* __restrict__ ssum, double* __restrict__ ssq)
{
    const int lane = threadIdx.x;
    const int g0 = blockIdx.x * 8;
    const int b = g0 / NN;
    double lsum = 0.0, lsq = 0.0;
    for (int ni = 0; ni < 8; ++ni) {
        const int g = g0 + ni;
        const float v = vb[(size_t)g*64 + lane];
        float vmax = -INFINITY;
        for (int k = 0; k < KK; ++k) {
            const int j = idx[(size_t)g*KK + k] & NMASK;
            float o = ub[(size_t)(b*NN + j)*64 + lane] + v;
            if constexpr (STOREMAX) vmax = fmaxf(vmax, o);
            lsum += (double)o; lsq += (double)o*(double)o;
        }
        if constexpr (STOREMAX) xraw[(size_t)g*64 + lane] = vmax;
    }
    atomicAdd(&ssum[b*64+lane], lsum);
    atomicAdd(&ssq [b*64+lane], lsq);
}

// ---------------- stage 1 pass B (exact, frozen): conv1 -> norm/lrelu -> conv2 ----------------
__global__ __launch_bounds__(64) void s1b_kernel(const float* __restrict__ x, const int* __restrict__ idx,
    const float* __restrict__ w1, const float* __restrict__ w2,
    const float* __restrict__ m1, const float* __restrict__ r1,
    float* __restrict__ xraw, double* __restrict__ ssum, double* __restrict__ ssq)
{
    __shared__ float sh[64];
    const int lane = threadIdx.x;
    float wr1[8];
#pragma unroll
    for (int c = 0; c < 8; ++c) wr1[c] = w1[lane*8 + c];
    float wr2[64];
#pragma unroll
    for (int c = 0; c < 64; ++c) wr2[c] = w2[lane*64 + c];
    const int g0 = blockIdx.x * 8;
    const int b = g0 / NN;
    const float mm = m1[b*64+lane], rr = r1[b*64+lane];
    double lsum = 0.0, lsq = 0.0;
    for (int ni = 0; ni < 8; ++ni) {
        const int g = g0 + ni;
        const float4 ct = *reinterpret_cast<const float4*>(x + (size_t)g*4);
        float vmax = -INFINITY;
        for (int k = 0; k < KK; ++k) {
            const int j = idx[(size_t)g*KK + k] & NMASK;
            const float4 nb = *reinterpret_cast<const float4*>(x + (size_t)(b*NN + j)*4);
            float o1 = wr1[0]*(nb.x-ct.x) + wr1[1]*(nb.y-ct.y) + wr1[2]*(nb.z-ct.z) + wr1[3]*(nb.w-ct.w)
                     + wr1[4]*ct.x + wr1[5]*ct.y + wr1[6]*ct.z + wr1[7]*ct.w;
            float h = lrelu_f((o1 - mm) * rr);
            __syncthreads();
            sh[lane] = h;
            __syncthreads();
            float acc = 0.f;
#pragma unroll
            for (int c = 0; c < 64; c += 4) {
                const float4 hv = *reinterpret_cast<const float4*>(&sh[c]);
                acc += wr2[c]*hv.x + wr2[c+1]*hv.y + wr2[c+2]*hv.z + wr2[c+3]*hv.w;
            }
            vmax = fmaxf(vmax, acc);
            lsum += (double)acc; lsq += (double)acc*(double)acc;
        }
        xraw[(size_t)g*64 + lane] = vmax;
    }
    atomicAdd(&ssum[b*64+lane], lsum);
    atomicAdd(&ssq [b*64+lane], lsq);
}

// ---------------- stage 2 pass B (exact, frozen): conv3 -> norm/lrelu -> conv4 ----------------
__global__ __launch_bounds__(64) void s2b_kernel(const float* __restrict__ xin, const int* __restrict__ idx,
    const float* __restrict__ w3, const float* __restrict__ w4,
    const float* __restrict__ m3, const float* __restrict__ r3,
    float* __restrict__ xraw, double* __restrict__ ssum, double* __restrict__ ssq)
{
    __shared__ float sf[128];
    __shared__ float sh[64];
    const int lane = threadIdx.x;
    float wr3[128];
#pragma unroll
    for (int c = 0; c < 128; ++c) wr3[c] = w3[lane*128 + c];
    float wr4[64];
#pragma unroll
    for (int c = 0; c < 64; ++c) wr4[c] = w4[lane*64 + c];
    const int g0 = blockIdx.x * 8;
    const int b = g0 / NN;
    const float mm = m3[b*64+lane], rr = r3[b*64+lane];
    double lsum = 0.0, lsq = 0.0;
    for (int ni = 0; ni < 8; ++ni) {
        const int g = g0 + ni;
        const float ctl = xin[(size_t)g*64 + lane];
        float vmax = -INFINITY;
        for (int k = 0; k < KK; ++k) {
            const int j = idx[(size_t)g*KK + k] & NMASK;
            const float nbl = xin[(size_t)(b*NN + j)*64 + lane];
            __syncthreads();
            sf[lane] = nbl - ctl;
            sf[64+lane] = ctl;
            __syncthreads();
            float o3 = 0.f;
#pragma unroll
            for (int c = 0; c < 128; c += 4) {
                const float4 fv = *reinterpret_cast<const float4*>(&sf[c]);
                o3 += wr3[c]*fv.x + wr3[c+1]*fv.y + wr3[c+2]*fv.z + wr3[c+3]*fv.w;
            }
            float h = lrelu_f((o3 - mm) * rr);
            __syncthreads();
            sh[lane] = h;
            __syncthreads();
            float acc = 0.f;
#pragma unroll
            for (int c = 0; c < 64; c += 4) {
                const float4 hv = *reinterpret_cast<const float4*>(&sh[c]);
                acc += wr4[c]*hv.x + wr4[c+1]*hv.y + wr4[c+2]*hv.z + wr4[c+3]*hv.w;
            }
            vmax = fmaxf(vmax, acc);
            lsum += (double)acc; lsq += (double)acc*(double)acc;
        }
        xraw[(size_t)g*64 + lane] = vmax;
    }
    atomicAdd(&ssum[b*64+lane], lsum);
    atomicAdd(&ssq [b*64+lane], lsq);
}

// ---------------- stats finalize ----------------
__global__ void fin_kernel(const double* __restrict__ ssum, const double* __restrict__ ssq,
                           float* __restrict__ meanp, float* __restrict__ rstdp, int total, double invn)
{
    int t = blockIdx.x*256 + threadIdx.x;
    if (t >= total) return;
    double m = ssum[t]*invn;
    double v = ssq[t]*invn - m*m;
    meanp[t] = (float)m;
    rstdp[t] = (float)(1.0 / sqrt(v + 1e-5));
}

// float4 finx: bit-identical per element (elementwise op)
__global__ void finx_kernel(float* __restrict__ xv, const float* __restrict__ m, const float* __restrict__ r)
{
    int t = blockIdx.x*256 + threadIdx.x;   // over B*NN*16 float4s
    int c0 = (t & 15) * 4;
    int b = t >> 16;                        // NN*16 float4s per batch
    float4 v = *reinterpret_cast<float4*>(xv + (size_t)t*4);
    v.x = lrelu_f((v.x - m[b*64+c0+0]) * r[b*64+c0+0]);
    v.y = lrelu_f((v.y - m[b*64+c0+1]) * r[b*64+c0+1]);
    v.z = lrelu_f((v.z - m[b*64+c0+2]) * r[b*64+c0+2]);
    v.w = lrelu_f((v.w - m[b*64+c0+3]) * r[b*64+c0+3]);
    *reinterpret_cast<float4*>(xv + (size_t)t*4) = v;
}

__global__ void transw_kernel(const float* __restrict__ w, float* __restrict__ wT, int O, int C, int rs, int off)
{
    int t = blockIdx.x*256 + threadIdx.x;
    if (t >= O*C) return;
    int o = t % O, c = t / O;
    wT[t] = w[(size_t)o*rs + off + c];
}

// conv7 pass A: 192(cat) -> 512 (g-broadcast term cancels exactly under in1d), stats + out7 fp16
__global__ __launch_bounds__(256) void conv7a_kernel(
    const float* __restrict__ x1, const float* __restrict__ x2, const float* __restrict__ x3,
    const float* __restrict__ wT,
    __half* __restrict__ out7h, double* __restrict__ ssum, double* __restrict__ ssq)
{
    __shared__ float si[32][192];
    const int b = blockIdx.z, nbase = blockIdx.x*32;
    const int o = blockIdx.y*256 + threadIdx.x;
    for (int i = threadIdx.x; i < 32*192; i += 256) {
        int nl = i/192, c = i%192;
        size_t base = (size_t)(b*NN + nbase + nl)*64;
        si[nl][c] = (c < 64) ? x1[base + c] : (c < 128) ? x2[base + c - 64] : x3[base + c - 128];
    }
    __syncthreads();
    float acc[32];
#pragma unroll
    for (int n = 0; n < 32; ++n) acc[n] = 0.f;
    for (int c = 0; c < 192; ++c) {
        float wv = wT[(size_t)c*512 + o];
#pragma unroll
        for (int n = 0; n < 32; ++n) acc[n] = fmaf(wv, si[n][c], acc[n]);
    }
    double ps = 0.0, pq = 0.0;
#pragma unroll
    for (int n = 0; n < 32; ++n) {
        out7h[(size_t)(b*NN + nbase + n)*512 + o] = __float2half(acc[n]);
        ps += (double)acc[n]; pq += (double)acc[n]*(double)acc[n];
    }
    atomicAdd(&ssum[b*512+o], ps);
    atomicAdd(&ssq [b*512+o], pq);
}

// conv8 only: read out7h, norm+lrelu -> LDS, conv8 -> out8 + stats8
__global__ __launch_bounds__(256) void conv8k_kernel(
    const __half* __restrict__ out7h, const float* __restrict__ m7, const float* __restrict__ r7,
    const float* __restrict__ wT8,
    float* __restrict__ out8, double* __restrict__ ssum, double* __restrict__ ssq)
{
    __shared__ float h7[16][512];    // 32 KB
    const int b = blockIdx.y, nbase = blockIdx.x*16;
    const int tid = threadIdx.x;
    for (int i = tid; i < 16*512; i += 256) {
        int nl = i >> 9, c = i & 511;
        float v = __half2float(out7h[(size_t)(b*NN + nbase + nl)*512 + c]);
        h7[nl][c] = lrelu_f((v - m7[b*512+c]) * r7[b*512+c]);
    }
    __syncthreads();
    const int o = tid;
    float acc8[16];
#pragma unroll
    for (int n = 0; n < 16; ++n) acc8[n] = 0.f;
    for (int c = 0; c < 512; ++c) {
        float wv = wT8[(size_t)c*256 + o];
#pragma unroll
        for (int n = 0; n < 16; ++n) acc8[n] = fmaf(wv, h7[n][c], acc8[n]);
    }
    double ps = 0.0, pq = 0.0;
#pragma unroll
    for (int n = 0; n < 16; ++n) {
        out8[(size_t)(b*NN + nbase + n)*256 + o] = acc8[n];
        ps += (double)acc8[n]; pq += (double)acc8[n]*(double)acc8[n];
    }
    atomicAdd(&ssum[b*256+o], ps);
    atomicAdd(&ssq [b*256+o], pq);
}

// conv9: 256 -> 2
__global__ __launch_bounds__(256) void conv9_kernel(const float* __restrict__ in8,
    const float* __restrict__ meanp, const float* __restrict__ rstdp,
    const float* __restrict__ w9, float* __restrict__ outp)
{
    const int lane = threadIdx.x & 63, wv = threadIdx.x >> 6;
    const int ng = blockIdx.x*4 + wv;
    const int b = ng / NN;
    const int c0 = lane*4;
    const float4 v4 = *reinterpret_cast<const float4*>(&in8[(size_t)ng*256 + c0]);
    float vv[4] = {v4.x, v4.y, v4.z, v4.w};
    float a0 = 0.f, a1 = 0.f;
#pragma unroll
    for (int i = 0; i < 4; ++i) {
        int c = c0 + i;
        float a = lrelu_f((vv[i] - meanp[b*256+c]) * rstdp[b*256+c]);
        a0 = fmaf(w9[c],     a, a0);
        a1 = fmaf(w9[256+c], a, a1);
    }
#pragma unroll
    for (int off = 32; off > 0; off >>= 1) {
        a0 += __shfl_down(a0, off, 64);
        a1 += __shfl_down(a1, off, 64);
    }
    if (lane == 0) { outp[(size_t)ng*2 + 0] = a0; outp[(size_t)ng*2 + 1] = a1; }
}

extern "C" void kernel_launch(void* const* d_in, const int* in_sizes, int n_in,
                              void* d_out, int out_size, void* d_ws, size_t ws_size,
                              hipStream_t stream)
{
    const float* x  = (const float*)d_in[0];
    const float* w1 = (const float*)d_in[1];
    const float* w2 = (const float*)d_in[2];
    const float* w3 = (const float*)d_in[3];
    const float* w4 = (const float*)d_in[4];
    const float* w5 = (const float*)d_in[5];
    const float* w7 = (const float*)d_in[7];
    const float* w8 = (const float*)d_in[8];
    const float* w9 = (const float*)d_in[9];
    float* outp = (float*)d_out;

    char* ws = (char*)d_ws;
    size_t off = 0;
    auto alloc = [&](size_t bytes) -> void* {
        void* p = ws + off;
        off = (off + bytes + 255) & ~(size_t)255;
        return p;
    };
    double* dstats = (double*)alloc((size_t)16896 * 8);
    unsigned* u6max = (unsigned*)alloc((size_t)4096 * 4);   // layout stability (unused)
    float* fstats = (float*)alloc((size_t)14848 * 4);
    int*   idxb  = (int*)  alloc((size_t)TPOS * 4);
    float* wT7   = (float*)alloc((size_t)512*192*4);
    float* wT8   = (float*)alloc((size_t)256*512*4);
    // union region: ubuf+vbuf (stages) / out7h (head)
    char*  sc17  = (char*) alloc((size_t)BB*NN*512*2);
    float* ubuf  = (float*)sc17;
    float* vbuf  = (float*)(sc17 + (size_t)BB*NN*64*4);
    __half* out7h = (__half*)sc17;
    float* x1v   = (float*)alloc((size_t)BB*NN*64*4);
    float* x2v   = (float*)alloc((size_t)BB*NN*64*4);
    float* x3v   = (float*)alloc((size_t)BB*NN*64*4);
    float* out8  = (float*)alloc((size_t)BB*NN*256*4);

    (void)u6max;
    double* d1 = dstats;           double* d2 = dstats + 512;
    double* d3 = dstats + 1024;    double* d4 = dstats + 1536;
    double* d5 = dstats + 2048;
    double* d7sum = dstats + 10752; double* d7sq = d7sum + 2048;
    double* d8sum = dstats + 14848; double* d8sq = d8sum + 1024;
    float* m1 = fstats;        float* r1 = fstats + 256;
    float* m2 = fstats + 512;  float* r2 = fstats + 768;
    float* m3 = fstats + 1024; float* r3 = fstats + 1280;
    float* m4 = fstats + 1536; float* r4 = fstats + 1792;
    float* m5 = fstats + 2048; float* r5 = fstats + 2304;
    float* m7 = fstats + 6656; float* r7 = fstats + 8704;
    float* m8 = fstats + 12800; float* r8 = fstats + 13824;

    hipMemsetAsync(dstats, 0, (size_t)16896*8 + (size_t)4096*4, stream);

    transw_kernel<<<384, 256, 0, stream>>>(w7, wT7, 512, 192, 1216, 1024);
    transw_kernel<<<512, 256, 0, stream>>>(w8, wT8, 256, 512, 512, 0);

    // ---- stage 1 ----
    knn_kernel<4><<<1024, 256, 0, stream>>>(x, idxb);
    uv_kernel<4, 4><<<512, 64, 0, stream>>>(x, w1, ubuf, vbuf);
    gstat_kernel<false><<<2048, 64, 0, stream>>>(ubuf, vbuf, idxb, nullptr, d1, d1+256);
    fin_kernel<<<1, 256, 0, stream>>>(d1, d1+256, m1, r1, 256, 1.0/81920.0);
    s1b_kernel<<<2048, 64, 0, stream>>>(x, idxb, w1, w2, m1, r1, x1v, d2, d2+256);
    fin_kernel<<<1, 256, 0, stream>>>(d2, d2+256, m2, r2, 256, 1.0/81920.0);
    finx_kernel<<<1024, 256, 0, stream>>>(x1v, m2, r2);

    // ---- stage 2 ----
    knn_kernel<64><<<1024, 256, 0, stream>>>(x1v, idxb);
    uv_kernel<64, 64><<<512, 64, 0, stream>>>(x1v, w3, ubuf, vbuf);
    gstat_kernel<false><<<2048, 64, 0, stream>>>(ubuf, vbuf, idxb, nullptr, d3, d3+256);
    fin_kernel<<<1, 256, 0, stream>>>(d3, d3+256, m3, r3, 256, 1.0/81920.0);
    s2b_kernel<<<2048, 64, 0, stream>>>(x1v, idxb, w3, w4, m3, r3, x2v, d4, d4+256);
    fin_kernel<<<1, 256, 0, stream>>>(d4, d4+256, m4, r4, 256, 1.0/81920.0);
    finx_kernel<<<1024, 256, 0, stream>>>(x2v, m4, r4);

    // ---- stage 3: fully u/v (x3v feeds no kNN) ----
    knn_kernel<64><<<1024, 256, 0, stream>>>(x2v, idxb);
    uv_kernel<64, 64><<<512, 64, 0, stream>>>(x2v, w5, ubuf, vbuf);
    gstat_kernel<true><<<2048, 64, 0, stream>>>(ubuf, vbuf, idxb, x3v, d5, d5+256);
    fin_kernel<<<1, 256, 0, stream>>>(d5, d5+256, m5, r5, 256, 1.0/81920.0);
    finx_kernel<<<1024, 256, 0, stream>>>(x3v, m5, r5);

    // ---- head (conv6/g path dropped: cancels exactly under in1d) ----
    conv7a_kernel<<<dim3(128, 2, 4), 256, 0, stream>>>(x1v, x2v, x3v, wT7, out7h, d7sum, d7sq);
    fin_kernel<<<8, 256, 0, stream>>>(d7sum, d7sq, m7, r7, 2048, 1.0/4096.0);
    conv8k_kernel<<<dim3(256, 4), 256, 0, stream>>>(out7h, m7, r7, wT8, out8, d8sum, d8sq);
    fin_kernel<<<4, 256, 0, stream>>>(d8sum, d8sq, m8, r8, 1024, 1.0/4096.0);
    conv9_kernel<<<4096, 256, 0, stream>>>(out8, m8, r8, w9, outp);
}